// Round 1
// baseline (427.502 us; speedup 1.0000x reference)
//
#include <hip/hip_runtime.h>
#include <hip/hip_bf16.h>

// Problem: B=8, C=512, H=W=64, K=3 depthwise-dynamic conv + shared 3x3 conv.
// Pipeline: k_stats (IN mean/rstd) -> k_wprep (conv_w -> bf16 wT[t][o][c])
//           k_mid (fused IN+dw3x3+pw+bias -> mid bf16 [b][h][w][c])
//           k_conv (implicit-GEMM 3x3 conv via MFMA 16x16x32 bf16)

#define EPSV 1e-5f

typedef __attribute__((ext_vector_type(8))) short short8;
typedef __attribute__((ext_vector_type(4))) float f32x4;

__device__ __forceinline__ unsigned short f2bf(float f) {
  union { float f; unsigned int u; } v; v.f = f;
  unsigned int r = v.u + 0x7FFFu + ((v.u >> 16) & 1u);   // RNE
  return (unsigned short)(r >> 16);
}

__device__ __forceinline__ int refl(int i, int n) {
  if (i < 0) i = -i;
  if (i >= n) i = 2 * n - 2 - i;
  return i;
}

// ---------------- kernel 1: instance-norm stats ----------------
__global__ __launch_bounds__(256) void k_stats(const float* __restrict__ x,
                                               float* __restrict__ mean,
                                               float* __restrict__ rstd) {
  int bc = blockIdx.x;                       // b*512 + c, 0..4095
  const float4* xp = (const float4*)(x + (size_t)bc * 4096);
  int tid = threadIdx.x;
  float s = 0.f, q = 0.f;
#pragma unroll
  for (int k = 0; k < 4; ++k) {
    float4 v = xp[tid + k * 256];
    s += v.x + v.y + v.z + v.w;
    q += v.x * v.x + v.y * v.y + v.z * v.z + v.w * v.w;
  }
  __shared__ float s1[256], s2[256];
  s1[tid] = s; s2[tid] = q;
  __syncthreads();
  for (int st = 128; st > 0; st >>= 1) {
    if (tid < st) { s1[tid] += s1[tid + st]; s2[tid] += s2[tid + st]; }
    __syncthreads();
  }
  if (tid == 0) {
    float m = s1[0] * (1.f / 4096.f);
    float var = s2[0] * (1.f / 4096.f) - m * m;
    mean[bc] = m;
    rstd[bc] = rsqrtf(var + EPSV);
  }
}

// ---------------- kernel 2: weight transform conv_w[o][c][3][3] -> wT[t][o][c] bf16
__global__ __launch_bounds__(256) void k_wprep(const float* __restrict__ cw,
                                               unsigned short* __restrict__ wT) {
  int idx = blockIdx.x * 256 + threadIdx.x;  // exactly 9*512*512
  int c = idx & 511;
  int o = (idx >> 9) & 511;
  int t = idx >> 18;
  wT[idx] = f2bf(cw[((size_t)(o * 512 + c)) * 9 + t]);
}

// ---------------- kernel 3: fused IN + depthwise + pointwise + bias -> mid bf16 [b][h][w][c]
__global__ __launch_bounds__(256) void k_mid(const float* __restrict__ x,
                                             const float* __restrict__ wsp,
                                             const float* __restrict__ wpw,
                                             const float* __restrict__ bias,
                                             const float* __restrict__ mean,
                                             const float* __restrict__ rstd,
                                             unsigned short* __restrict__ mid) {
  int bh = blockIdx.x;                       // b*64 + h
  int b = bh >> 6, h = bh & 63;
  int tid = threadIdx.x;
  int cl = tid & 31, wq = tid >> 5;          // 32 channels x 8 w-lanes
  __shared__ float xs[32 * 195];             // [c][3*65] padded rows
  int r0 = refl(h - 1, 64), r2 = refl(h + 1, 64);

  for (int cc = 0; cc < 16; ++cc) {
    int cbase = cc * 32;
    __syncthreads();
    // stage 32 channels x 3 rows x 64 w
    for (int idx = tid; idx < 32 * 192; idx += 256) {
      int c = idx / 192, rem = idx % 192, r = rem >> 6, w = rem & 63;
      int row = (r == 0) ? r0 : ((r == 1) ? h : r2);
      xs[c * 195 + r * 65 + w] =
          x[(((size_t)(b * 512 + cbase + c)) * 64 + row) * 64 + w];
    }
    __syncthreads();

    int gc = b * 512 + cbase + cl;
    float m = mean[gc], rs = rstd[gc];
    float wp = wpw[gc], bv = bias[gc];
    float wk[9], wsum = 0.f;
#pragma unroll
    for (int t = 0; t < 9; ++t) { wk[t] = wsp[(size_t)gc * 9 + t]; wsum += wk[t]; }

    const float* xr = &xs[cl * 195];
#pragma unroll
    for (int wi = 0; wi < 8; ++wi) {
      int w = wq * 8 + wi;
      int wm = refl(w - 1, 64), wp1 = refl(w + 1, 64);
      float acc = 0.f;
#pragma unroll
      for (int dy = 0; dy < 3; ++dy) {
        const float* row = xr + dy * 65;
        acc += wk[dy * 3 + 0] * row[wm] + wk[dy * 3 + 1] * row[w] +
               wk[dy * 3 + 2] * row[wp1];
      }
      float y = (acc - m * wsum) * rs;       // normalized depthwise output
      float mv = y * wp + bv;
      mid[(((size_t)(b * 64 + h)) * 64 + w) * 512 + cbase + cl] = f2bf(mv);
    }
  }
}

// ---------------- kernel 4: final 3x3 conv as implicit GEMM (MFMA bf16) ----------------
// out[b][o][h][w] = sum_{c,dy,dx} wT[t][o][c] * mid[b][h+dy-1][w+dx-1][c] + cb[o]
// Block: 128 o x (2 rows x 64 w). 4 waves, each 64o x 64pix. K-loop: c chunks of 64.
__global__ __launch_bounds__(256) void k_conv(const unsigned short* __restrict__ wT,
                                              const unsigned short* __restrict__ mid,
                                              const float* __restrict__ cb,
                                              float* __restrict__ out) {
  int bid = blockIdx.x;                      // 1024 = 4 mtiles * 8 b * 32 rowpairs
  int mt = bid & 3;
  int rest = bid >> 2;
  int b = rest >> 5;
  int h0 = (rest & 31) * 2;
  int tid = threadIdx.x;
  int wid = tid >> 6, l = tid & 63;
  int wo = wid >> 1, wn = wid & 1;           // wave tile: (wo: o-half, wn: row)
  int l15 = l & 15, g = l >> 4;
  int o0 = mt * 128;

  __shared__ unsigned short mt_lds[4 * 64 * 64];   // 4 rows x 64 w x 64 c = 32 KB
  char* mb = (char*)mt_lds;

  // per-lane reflected w for each (nf, dx)
  int wrv[4][3];
#pragma unroll
  for (int nf = 0; nf < 4; ++nf)
#pragma unroll
    for (int dx = 0; dx < 3; ++dx)
      wrv[nf][dx] = refl(nf * 16 + l15 + dx - 1, 64);

  f32x4 acc[4][4];
  f32x4 zero = {0.f, 0.f, 0.f, 0.f};
#pragma unroll
  for (int i = 0; i < 4; ++i)
#pragma unroll
    for (int j = 0; j < 4; ++j) acc[i][j] = zero;

  for (int cc2 = 0; cc2 < 8; ++cc2) {
    int cb64 = cc2 * 64;
    __syncthreads();
    // stage mid tile: rows h0-1..h0+2 (reflected), w 0..63, c chunk of 64.
    // LDS layout [row][w][slot*8], slot holds global c-group (slot ^ (w&7))  (bank swizzle)
#pragma unroll
    for (int i = 0; i < 8; ++i) {
      int ch = tid + i * 256;                // 0..2047
      int row = ch >> 9, rem = ch & 511, w = rem >> 3, cg = rem & 7;
      int hrow = refl(h0 - 1 + row, 64);
      int gcg = cg ^ (w & 7);
      const short8* src = (const short8*)(mid +
          (((size_t)(b * 64 + hrow)) * 64 + w) * 512 + cb64 + gcg * 8);
      *(short8*)(mb + ch * 16) = *src;
    }
    __syncthreads();

#pragma unroll
    for (int t = 0; t < 9; ++t) {
      const int dy = t / 3, dx = t % 3;
      const int rowL = wn + dy;              // 0..3 staged row
      const unsigned short* wa = wT + (size_t)t * 262144 +
          ((size_t)(o0 + wo * 64 + l15)) * 512 + cb64 + g * 8;
#pragma unroll
      for (int kk = 0; kk < 2; ++kk) {
        short8 bfr[4];
#pragma unroll
        for (int nf = 0; nf < 4; ++nf) {
          int wr = wrv[nf][dx];
          int slot = ((kk << 2) + g) ^ (wr & 7);
          bfr[nf] = *(const short8*)(mb + rowL * 8192 + wr * 128 + slot * 16);
        }
#pragma unroll
        for (int of = 0; of < 4; ++of) {
          short8 afr = *(const short8*)(wa + of * 16 * 512 + kk * 32);
#pragma unroll
          for (int nf = 0; nf < 4; ++nf)
            acc[of][nf] = __builtin_amdgcn_mfma_f32_16x16x32_bf16(
                afr, bfr[nf], acc[of][nf], 0, 0, 0);
        }
      }
    }
  }

  // epilogue: D[row=g*4+r][col=l15], add conv bias
  int obase = o0 + wo * 64;
  int h = h0 + wn;
#pragma unroll
  for (int of = 0; of < 4; ++of) {
#pragma unroll
    for (int nf = 0; nf < 4; ++nf) {
      int w = nf * 16 + l15;
#pragma unroll
      for (int r = 0; r < 4; ++r) {
        int o = obase + of * 16 + g * 4 + r;
        out[(((size_t)(b * 512 + o)) * 64 + h) * 64 + w] = acc[of][nf][r] + cb[o];
      }
    }
  }
}

extern "C" void kernel_launch(void* const* d_in, const int* in_sizes, int n_in,
                              void* d_out, int out_size, void* d_ws, size_t ws_size,
                              hipStream_t stream) {
  const float* x    = (const float*)d_in[0];
  const float* wsp  = (const float*)d_in[1];
  const float* wpw  = (const float*)d_in[2];
  const float* bias = (const float*)d_in[3];
  const float* cw   = (const float*)d_in[4];
  const float* cb   = (const float*)d_in[5];
  float* out = (float*)d_out;

  char* ws = (char*)d_ws;
  float* mean = (float*)ws;                              // 4096 f32
  float* rstd = (float*)(ws + 16384);                    // 4096 f32
  unsigned short* wT  = (unsigned short*)(ws + 32768);   // 9*512*512 bf16 = 4.5 MB
  unsigned short* mid = (unsigned short*)(ws + 32768 + 9 * 512 * 512 * 2); // 32 MB

  k_stats<<<4096, 256, 0, stream>>>(x, mean, rstd);
  k_wprep<<<9216, 256, 0, stream>>>(cw, wT);
  k_mid<<<512, 256, 0, stream>>>(x, wsp, wpw, bias, mean, rstd, mid);
  k_conv<<<1024, 256, 0, stream>>>(wT, mid, cb, out);
}

// Round 2
// 378.902 us; speedup vs baseline: 1.1283x; 1.1283x over previous
//
#include <hip/hip_runtime.h>
#include <hip/hip_bf16.h>

// Pipeline: k_stats (IN mean/rstd) -> k_wprep (conv_w -> bf16 wT2 fragment layout)
//           k_mid (fused IN+dw3x3+pw+bias -> mid bf16 [b][h][w][c], 4 rows/block)
//           k_conv (implicit-GEMM 3x3 conv, MFMA 16x16x32, 2-phase gload_lds pipeline)

#define EPSV 1e-5f

typedef __attribute__((ext_vector_type(8))) short short8;
typedef __attribute__((ext_vector_type(4))) float f32x4;

__device__ __forceinline__ unsigned short f2bf(float f) {
  union { float f; unsigned int u; } v; v.f = f;
  unsigned int r = v.u + 0x7FFFu + ((v.u >> 16) & 1u);   // RNE
  return (unsigned short)(r >> 16);
}

__device__ __forceinline__ int refl(int i, int n) {
  if (i < 0) i = -i;
  if (i >= n) i = 2 * n - 2 - i;
  return i;
}

// ---------------- kernel 1: instance-norm stats ----------------
__global__ __launch_bounds__(256) void k_stats(const float* __restrict__ x,
                                               float* __restrict__ mean,
                                               float* __restrict__ rstd) {
  int bc = blockIdx.x;                       // b*512 + c
  const float4* xp = (const float4*)(x + (size_t)bc * 4096);
  int tid = threadIdx.x;
  float s = 0.f, q = 0.f;
#pragma unroll
  for (int k = 0; k < 4; ++k) {
    float4 v = xp[tid + k * 256];
    s += v.x + v.y + v.z + v.w;
    q += v.x * v.x + v.y * v.y + v.z * v.z + v.w * v.w;
  }
  __shared__ float s1[256], s2[256];
  s1[tid] = s; s2[tid] = q;
  __syncthreads();
  for (int st = 128; st > 0; st >>= 1) {
    if (tid < st) { s1[tid] += s1[tid + st]; s2[tid] += s2[tid + st]; }
    __syncthreads();
  }
  if (tid == 0) {
    float m = s1[0] * (1.f / 4096.f);
    float var = s2[0] * (1.f / 4096.f) - m * m;
    mean[bc] = m;
    rstd[bc] = rsqrtf(var + EPSV);
  }
}

// ---------------- kernel 2: conv_w[o][c][3][3] -> wT2 MFMA-fragment layout bf16
// wT2 flat idx = ((((t*32 + o/16)*16 + c/32)*64) + (g*16 + o%16))*8 + e
//   where g = (c%32)/8, e = c%8.  A wave's A-frag load is then 1KB contiguous.
__global__ __launch_bounds__(256) void k_wprep(const float* __restrict__ cw,
                                               unsigned short* __restrict__ wT2) {
  int idx = blockIdx.x * 256 + threadIdx.x;  // 9*512*512 = 2359296
  int e = idx & 7;
  int l15 = (idx >> 3) & 15;
  int g = (idx >> 7) & 3;
  int cq = (idx >> 9) & 15;
  int og = (idx >> 13) & 31;
  int t = idx >> 18;
  int o = og * 16 + l15;
  int c = cq * 32 + g * 8 + e;
  wT2[idx] = f2bf(cw[((size_t)(o * 512 + c)) * 9 + t]);
}

// ---------------- kernel 3: fused IN + dw3x3 + pointwise + bias -> mid bf16 [b][h][w][c]
// block = (b, h-quad of 4 rows, c-group of 128); stages 6 halo rows x 32 c per chunk.
__global__ __launch_bounds__(256) void k_mid(const float* __restrict__ x,
                                             const float* __restrict__ wsp,
                                             const float* __restrict__ wpw,
                                             const float* __restrict__ bias,
                                             const float* __restrict__ mean,
                                             const float* __restrict__ rstd,
                                             unsigned short* __restrict__ mid) {
  int bid = blockIdx.x;                      // 8 * 16 * 4 = 512
  int cg = bid & 3;
  int hq = (bid >> 2) & 15;
  int b = bid >> 6;
  int h0 = hq * 4;
  int tid = threadIdx.x;
  int cl = tid & 31, wq = tid >> 5;          // 32 channels x 8 w-lanes
  __shared__ float xs[32 * 391];             // c-stride 391 (odd), row-stride 65

  int rowm[6];
#pragma unroll
  for (int r = 0; r < 6; ++r) rowm[r] = refl(h0 - 1 + r, 64);

  for (int cc = 0; cc < 4; ++cc) {
    int cbase = cg * 128 + cc * 32;
    __syncthreads();
    // stage 32 channels x 6 rows x 64 w, float4 global loads
#pragma unroll
    for (int k = 0; k < 12; ++k) {
      int idx = tid + k * 256;               // 0..3071 = (c, r, w4)
      int c = idx / 96, rem = idx % 96;
      int r = rem >> 4, w4 = rem & 15;
      float4 v = *(const float4*)(x + ((size_t)(b * 512 + cbase + c)) * 4096 +
                                  rowm[r] * 64 + w4 * 4);
      float* dst = &xs[c * 391 + r * 65 + w4 * 4];
      dst[0] = v.x; dst[1] = v.y; dst[2] = v.z; dst[3] = v.w;
    }
    __syncthreads();

    int gc = b * 512 + cbase + cl;
    float m = mean[gc], rs = rstd[gc];
    float wp = wpw[gc], bv = bias[gc];
    float wk[9], wsum = 0.f;
#pragma unroll
    for (int t = 0; t < 9; ++t) { wk[t] = wsp[(size_t)gc * 9 + t]; wsum += wk[t]; }

    const float* xr = &xs[cl * 391];
#pragma unroll
    for (int r = 0; r < 4; ++r) {
#pragma unroll
      for (int wi = 0; wi < 8; ++wi) {
        int w = wq * 8 + wi;
        int wm = refl(w - 1, 64), wp1 = refl(w + 1, 64);
        float acc = 0.f;
#pragma unroll
        for (int dy = 0; dy < 3; ++dy) {
          const float* row = xr + (r + dy) * 65;
          acc += wk[dy * 3 + 0] * row[wm] + wk[dy * 3 + 1] * row[w] +
                 wk[dy * 3 + 2] * row[wp1];
        }
        float y = (acc - m * wsum) * rs;
        mid[(((size_t)(b * 64 + h0 + r)) * 64 + w) * 512 + cbase + cl] =
            f2bf(y * wp + bv);
      }
    }
  }
}

// ---------------- kernel 4: final 3x3 conv, implicit GEMM, 2-phase pipelined ----------------
__global__ __launch_bounds__(256) void k_conv(const unsigned short* __restrict__ wT2,
                                              const unsigned short* __restrict__ mid,
                                              const float* __restrict__ cb,
                                              float* __restrict__ out) {
  int bid = blockIdx.x;                      // 1024 = 4 mtiles * 8 b * 32 rowpairs
  int mt = bid & 3;
  int rest = bid >> 2;
  int b = rest >> 5;
  int h0 = (rest & 31) * 2;
  int tid = threadIdx.x;
  int wid = tid >> 6, l = tid & 63;
  int wo = wid >> 1, wn = wid & 1;
  int l15 = l & 15, g = l >> 4;

  __shared__ unsigned short mt_lds[2][4 * 64 * 64];   // 2 x 32 KB double buffer

  int hrow_[4];
  hrow_[0] = refl(h0 - 1, 64); hrow_[1] = h0; hrow_[2] = h0 + 1;
  hrow_[3] = refl(h0 + 2, 64);

  int wrv[4][3];
#pragma unroll
  for (int nf = 0; nf < 4; ++nf)
#pragma unroll
    for (int dx = 0; dx < 3; ++dx)
      wrv[nf][dx] = refl(nf * 16 + l15 + dx - 1, 64);

  f32x4 acc[4][4];
  f32x4 zero = {0.f, 0.f, 0.f, 0.f};
#pragma unroll
  for (int i = 0; i < 4; ++i)
#pragma unroll
    for (int j = 0; j < 4; ++j) acc[i][j] = zero;

  // async stage of one 64-c chunk into LDS buffer bi (linear dest, swizzled src)
  auto stage = [&](int bi, int cc2) {
    int cb64 = cc2 * 64;
    char* dstbase = (char*)&mt_lds[bi][0];
#pragma unroll
    for (int i = 0; i < 8; ++i) {
      int ch = tid + i * 256;                // 0..2047
      int row = ch >> 9, rem = ch & 511, w = rem >> 3, cgi = rem & 7;
      int gcg = cgi ^ (w & 7);               // bank swizzle via pre-swizzled source
      const unsigned short* src = mid +
          (((size_t)(b * 64 + hrow_[row])) * 64 + w) * 512 + cb64 + gcg * 8;
      __builtin_amdgcn_global_load_lds(
          (const __attribute__((address_space(1))) void*)src,
          (__attribute__((address_space(3))) void*)(dstbase + ch * 16),
          16, 0, 0);
    }
  };

  stage(0, 0);
  int bi = 0;
  for (int cc2 = 0; cc2 < 8; ++cc2) {
    __syncthreads();                         // drains vmcnt(0): stage(cc2) landed
    if (cc2 < 7) stage(bi ^ 1, cc2 + 1);     // prefetch next chunk (in flight under compute)
    const char* mb = (const char*)&mt_lds[bi][0];
#pragma unroll
    for (int t = 0; t < 9; ++t) {
      const int dy = t / 3, dx = t % 3;
      const int rowL = wn + dy;
      const size_t abase = ((size_t)(t * 32 + mt * 8 + wo * 4) * 16) * 512;
#pragma unroll
      for (int kk = 0; kk < 2; ++kk) {
        short8 bfr[4];
#pragma unroll
        for (int nf = 0; nf < 4; ++nf) {
          int wr = wrv[nf][dx];
          int slot = ((kk << 2) + g) ^ (wr & 7);
          bfr[nf] = *(const short8*)(mb + rowL * 8192 + wr * 128 + slot * 16);
        }
#pragma unroll
        for (int of = 0; of < 4; ++of) {
          const short8 afr = *(const short8*)(wT2 + abase +
              ((size_t)(of * 16 + cc2 * 2 + kk)) * 512 + l * 8);
#pragma unroll
          for (int nf = 0; nf < 4; ++nf)
            acc[of][nf] = __builtin_amdgcn_mfma_f32_16x16x32_bf16(
                afr, bfr[nf], acc[of][nf], 0, 0, 0);
        }
      }
    }
    bi ^= 1;
  }

  // epilogue: D[row=g*4+r][col=l15], add conv bias
  int obase = mt * 128 + wo * 64;
  int h = h0 + wn;
#pragma unroll
  for (int of = 0; of < 4; ++of) {
#pragma unroll
    for (int nf = 0; nf < 4; ++nf) {
      int w = nf * 16 + l15;
#pragma unroll
      for (int r = 0; r < 4; ++r) {
        int o = obase + of * 16 + g * 4 + r;
        out[(((size_t)(b * 512 + o)) * 64 + h) * 64 + w] = acc[of][nf][r] + cb[o];
      }
    }
  }
}

extern "C" void kernel_launch(void* const* d_in, const int* in_sizes, int n_in,
                              void* d_out, int out_size, void* d_ws, size_t ws_size,
                              hipStream_t stream) {
  const float* x    = (const float*)d_in[0];
  const float* wsp  = (const float*)d_in[1];
  const float* wpw  = (const float*)d_in[2];
  const float* bias = (const float*)d_in[3];
  const float* cw   = (const float*)d_in[4];
  const float* cb   = (const float*)d_in[5];
  float* out = (float*)d_out;

  char* ws = (char*)d_ws;
  float* mean = (float*)ws;                              // 4096 f32
  float* rstd = (float*)(ws + 16384);                    // 4096 f32
  unsigned short* wT2 = (unsigned short*)(ws + 32768);   // 9*512*512 bf16 = 4.5 MB
  unsigned short* mid = (unsigned short*)(ws + 32768 + 9 * 512 * 512 * 2); // 32 MB

  k_stats<<<4096, 256, 0, stream>>>(x, mean, rstd);
  k_wprep<<<9216, 256, 0, stream>>>(cw, wT2);
  k_mid<<<512, 256, 0, stream>>>(x, wsp, wpw, bias, mean, rstd, mid);
  k_conv<<<1024, 256, 0, stream>>>(wT2, mid, cb, out);
}

// Round 3
// 341.050 us; speedup vs baseline: 1.2535x; 1.1110x over previous
//
#include <hip/hip_runtime.h>
#include <hip/hip_bf16.h>

// Pipeline: k_stats (IN mean/rstd) -> k_wprep (conv_w -> bf16 wT2 fragment layout)
//           k_mid (fused IN+dw3x3+pw+bias -> mid bf16 [b][h][w][c])
//           k_conv (implicit-GEMM 3x3 conv, MFMA 16x16x32, c32 chunks, 8-wave
//                   256o x 128pix blocks, XCD-chunked mt-slowest grid)

#define EPSV 1e-5f

typedef __attribute__((ext_vector_type(8))) short short8;
typedef __attribute__((ext_vector_type(4))) float f32x4;

__device__ __forceinline__ unsigned short f2bf(float f) {
  union { float f; unsigned int u; } v; v.f = f;
  unsigned int r = v.u + 0x7FFFu + ((v.u >> 16) & 1u);   // RNE
  return (unsigned short)(r >> 16);
}

__device__ __forceinline__ int refl(int i, int n) {
  if (i < 0) i = -i;
  if (i >= n) i = 2 * n - 2 - i;
  return i;
}

// ---------------- kernel 1: instance-norm stats ----------------
__global__ __launch_bounds__(256) void k_stats(const float* __restrict__ x,
                                               float* __restrict__ mean,
                                               float* __restrict__ rstd) {
  int bc = blockIdx.x;                       // b*512 + c
  const float4* xp = (const float4*)(x + (size_t)bc * 4096);
  int tid = threadIdx.x;
  float s = 0.f, q = 0.f;
#pragma unroll
  for (int k = 0; k < 4; ++k) {
    float4 v = xp[tid + k * 256];
    s += v.x + v.y + v.z + v.w;
    q += v.x * v.x + v.y * v.y + v.z * v.z + v.w * v.w;
  }
  __shared__ float s1[256], s2[256];
  s1[tid] = s; s2[tid] = q;
  __syncthreads();
  for (int st = 128; st > 0; st >>= 1) {
    if (tid < st) { s1[tid] += s1[tid + st]; s2[tid] += s2[tid + st]; }
    __syncthreads();
  }
  if (tid == 0) {
    float m = s1[0] * (1.f / 4096.f);
    float var = s2[0] * (1.f / 4096.f) - m * m;
    mean[bc] = m;
    rstd[bc] = rsqrtf(var + EPSV);
  }
}

// ---------------- kernel 2: conv_w[o][c][3][3] -> wT2 MFMA-fragment layout bf16
// flat = (((t*32 + o/16)*16 + c/32)*64 + (g*16 + o%16))*8 + e, g=(c%32)/8, e=c%8
__global__ __launch_bounds__(256) void k_wprep(const float* __restrict__ cw,
                                               unsigned short* __restrict__ wT2) {
  int idx = blockIdx.x * 256 + threadIdx.x;  // 9*512*512
  int e = idx & 7;
  int l15 = (idx >> 3) & 15;
  int g = (idx >> 7) & 3;
  int cq = (idx >> 9) & 15;
  int og = (idx >> 13) & 31;
  int t = idx >> 18;
  int o = og * 16 + l15;
  int c = cq * 32 + g * 8 + e;
  wT2[idx] = f2bf(cw[((size_t)(o * 512 + c)) * 9 + t]);
}

// ---------------- kernel 3: fused IN + dw3x3 + pointwise + bias -> mid bf16 [b][h][w][c]
__global__ __launch_bounds__(256) void k_mid(const float* __restrict__ x,
                                             const float* __restrict__ wsp,
                                             const float* __restrict__ wpw,
                                             const float* __restrict__ bias,
                                             const float* __restrict__ mean,
                                             const float* __restrict__ rstd,
                                             unsigned short* __restrict__ mid) {
  int bid = blockIdx.x;                      // 8 * 16 * 4 = 512
  int cg = bid & 3;
  int hq = (bid >> 2) & 15;
  int b = bid >> 6;
  int h0 = hq * 4;
  int tid = threadIdx.x;
  int cl = tid & 31, wq = tid >> 5;
  __shared__ float xs[32 * 391];             // c-stride 391 (odd), row-stride 65

  int rowm[6];
#pragma unroll
  for (int r = 0; r < 6; ++r) rowm[r] = refl(h0 - 1 + r, 64);

  for (int cc = 0; cc < 4; ++cc) {
    int cbase = cg * 128 + cc * 32;
    __syncthreads();
#pragma unroll
    for (int k = 0; k < 12; ++k) {
      int idx = tid + k * 256;               // (c, r, w4)
      int c = idx / 96, rem = idx % 96;
      int r = rem >> 4, w4 = rem & 15;
      float4 v = *(const float4*)(x + ((size_t)(b * 512 + cbase + c)) * 4096 +
                                  rowm[r] * 64 + w4 * 4);
      float* dst = &xs[c * 391 + r * 65 + w4 * 4];
      dst[0] = v.x; dst[1] = v.y; dst[2] = v.z; dst[3] = v.w;
    }
    __syncthreads();

    int gc = b * 512 + cbase + cl;
    float m = mean[gc], rs = rstd[gc];
    float wp = wpw[gc], bv = bias[gc];
    float wk[9], wsum = 0.f;
#pragma unroll
    for (int t = 0; t < 9; ++t) { wk[t] = wsp[(size_t)gc * 9 + t]; wsum += wk[t]; }

    const float* xr = &xs[cl * 391];
#pragma unroll
    for (int r = 0; r < 4; ++r) {
#pragma unroll
      for (int wi = 0; wi < 8; ++wi) {
        int w = wq * 8 + wi;
        int wm = refl(w - 1, 64), wp1 = refl(w + 1, 64);
        float acc = 0.f;
#pragma unroll
        for (int dy = 0; dy < 3; ++dy) {
          const float* row = xr + (r + dy) * 65;
          acc += wk[dy * 3 + 0] * row[wm] + wk[dy * 3 + 1] * row[w] +
                 wk[dy * 3 + 2] * row[wp1];
        }
        float y = (acc - m * wsum) * rs;
        mid[(((size_t)(b * 64 + h0 + r)) * 64 + w) * 512 + cbase + cl] =
            f2bf(y * wp + bv);
      }
    }
  }
}

// ---------------- kernel 4: final 3x3 conv, implicit GEMM ----------------
// grid 512; block = 8 waves = 256 o x (2 rows x 64 w). c-chunks of 32, dbuf LDS.
__global__ __launch_bounds__(512, 4) void k_conv(const unsigned short* __restrict__ wT2,
                                                 const unsigned short* __restrict__ mid,
                                                 const float* __restrict__ cb,
                                                 float* __restrict__ out) {
  // XCD-chunked bijective swizzle (512 = 8 xcd * 64), mt slowest for L2 weight reuse
  int nbid = (blockIdx.x & 7) * 64 + (blockIdx.x >> 3);
  int mt = nbid >> 8;                        // 0..1  (256 o each)
  int b = (nbid >> 5) & 7;
  int h0 = (nbid & 31) * 2;
  int tid = threadIdx.x;
  int wid = tid >> 6, l = tid & 63;
  int wo = wid >> 1, wn = wid & 1;           // wo: o-quarter (64 o), wn: row
  int l15 = l & 15, g = l >> 4;

  __shared__ unsigned short mt_lds[2][4 * 64 * 32];   // 2 x 16 KB double buffer

  int hrow_[4];
  hrow_[0] = refl(h0 - 1, 64); hrow_[1] = h0; hrow_[2] = h0 + 1;
  hrow_[3] = refl(h0 + 2, 64);

  int wrv[4][3];
#pragma unroll
  for (int nf = 0; nf < 4; ++nf)
#pragma unroll
    for (int dx = 0; dx < 3; ++dx)
      wrv[nf][dx] = refl(nf * 16 + l15 + dx - 1, 64);

  f32x4 acc[4][4];
  f32x4 zero = {0.f, 0.f, 0.f, 0.f};
#pragma unroll
  for (int i = 0; i < 4; ++i)
#pragma unroll
    for (int j = 0; j < 4; ++j) acc[i][j] = zero;

  // stage one 32-c chunk (4 rows x 64 w x 32 c = 16 KB): linear LDS dest,
  // bank swizzle via pre-swizzled global source: slot s holds c-group s^((w>>1)&3)
  auto stage = [&](int bi, int cc) {
    int cb32 = cc * 32;
    char* dstbase = (char*)&mt_lds[bi][0];
#pragma unroll
    for (int i = 0; i < 2; ++i) {
      int ld = tid + i * 512;                // 0..1023
      int row = ld >> 8, rem = ld & 255, w = rem >> 2, s = rem & 3;
      int gcg = s ^ ((w >> 1) & 3);
      const unsigned short* src = mid +
          (((size_t)(b * 64 + hrow_[row])) * 64 + w) * 512 + cb32 + gcg * 8;
      __builtin_amdgcn_global_load_lds(
          (const __attribute__((address_space(1))) void*)src,
          (__attribute__((address_space(3))) void*)(dstbase + ld * 16),
          16, 0, 0);
    }
  };

  stage(0, 0);
  int bi = 0;
  for (int cc = 0; cc < 16; ++cc) {
    __syncthreads();                         // stage(cc) landed
    if (cc < 15) stage(bi ^ 1, cc + 1);      // prefetch next chunk under compute
    const char* mb = (const char*)&mt_lds[bi][0];
#pragma unroll
    for (int t = 0; t < 9; ++t) {
      const int dy = t / 3, dx = t % 3;
      const int rowL = wn + dy;
      short8 bfr[4];
#pragma unroll
      for (int nf = 0; nf < 4; ++nf) {
        int wr = wrv[nf][dx];
        int s = g ^ ((wr >> 1) & 3);
        bfr[nf] = *(const short8*)(mb + rowL * 4096 + wr * 64 + s * 16);
      }
#pragma unroll
      for (int of = 0; of < 4; ++of) {
        const short8 afr = *(const short8*)(wT2 +
            (((size_t)(t * 32 + mt * 16 + wo * 4 + of)) * 16 + cc) * 512 + l * 8);
#pragma unroll
        for (int nf = 0; nf < 4; ++nf)
          acc[of][nf] = __builtin_amdgcn_mfma_f32_16x16x32_bf16(
              afr, bfr[nf], acc[of][nf], 0, 0, 0);
      }
    }
    bi ^= 1;
  }

  // epilogue: D[row=g*4+r][col=l15], add conv bias
  int obase = mt * 256 + wo * 64;
  int h = h0 + wn;
#pragma unroll
  for (int of = 0; of < 4; ++of) {
#pragma unroll
    for (int nf = 0; nf < 4; ++nf) {
      int w = nf * 16 + l15;
#pragma unroll
      for (int r = 0; r < 4; ++r) {
        int o = obase + of * 16 + g * 4 + r;
        out[(((size_t)(b * 512 + o)) * 64 + h) * 64 + w] = acc[of][nf][r] + cb[o];
      }
    }
  }
}

extern "C" void kernel_launch(void* const* d_in, const int* in_sizes, int n_in,
                              void* d_out, int out_size, void* d_ws, size_t ws_size,
                              hipStream_t stream) {
  const float* x    = (const float*)d_in[0];
  const float* wsp  = (const float*)d_in[1];
  const float* wpw  = (const float*)d_in[2];
  const float* bias = (const float*)d_in[3];
  const float* cw   = (const float*)d_in[4];
  const float* cb   = (const float*)d_in[5];
  float* out = (float*)d_out;

  char* ws = (char*)d_ws;
  float* mean = (float*)ws;                              // 4096 f32
  float* rstd = (float*)(ws + 16384);                    // 4096 f32
  unsigned short* wT2 = (unsigned short*)(ws + 32768);   // 4.5 MB
  unsigned short* mid = (unsigned short*)(ws + 32768 + 9 * 512 * 512 * 2); // 32 MB

  k_stats<<<4096, 256, 0, stream>>>(x, mean, rstd);
  k_wprep<<<9216, 256, 0, stream>>>(cw, wT2);
  k_mid<<<512, 256, 0, stream>>>(x, wsp, wpw, bias, mean, rstd, mid);
  k_conv<<<512, 512, 0, stream>>>(wT2, mid, cb, out);
}

// Round 4
// 286.740 us; speedup vs baseline: 1.4909x; 1.1894x over previous
//
#include <hip/hip_runtime.h>
#include <hip/hip_bf16.h>

// Pipeline: k_stats (IN mean/rstd) -> k_wprep (conv_w -> bf16 wT2 fragment layout)
//           k_mid (fused IN+dw3x3+pw+bias -> mid bf16 [b][h][w][c])
//           k_conv (implicit-GEMM 3x3 conv, MFMA 16x16x32; A and B both staged
//                   via async global_load_lds double-buffers; LDS-transposed epilogue)

#define EPSV 1e-5f

typedef __attribute__((ext_vector_type(8))) short short8;
typedef __attribute__((ext_vector_type(4))) float f32x4;

__device__ __forceinline__ unsigned short f2bf(float f) {
  union { float f; unsigned int u; } v; v.f = f;
  unsigned int r = v.u + 0x7FFFu + ((v.u >> 16) & 1u);   // RNE
  return (unsigned short)(r >> 16);
}

__device__ __forceinline__ int refl(int i, int n) {
  if (i < 0) i = -i;
  if (i >= n) i = 2 * n - 2 - i;
  return i;
}

// ---------------- kernel 1: instance-norm stats ----------------
__global__ __launch_bounds__(256) void k_stats(const float* __restrict__ x,
                                               float* __restrict__ mean,
                                               float* __restrict__ rstd) {
  int bc = blockIdx.x;
  const float4* xp = (const float4*)(x + (size_t)bc * 4096);
  int tid = threadIdx.x;
  float s = 0.f, q = 0.f;
#pragma unroll
  for (int k = 0; k < 4; ++k) {
    float4 v = xp[tid + k * 256];
    s += v.x + v.y + v.z + v.w;
    q += v.x * v.x + v.y * v.y + v.z * v.z + v.w * v.w;
  }
  __shared__ float s1[256], s2[256];
  s1[tid] = s; s2[tid] = q;
  __syncthreads();
  for (int st = 128; st > 0; st >>= 1) {
    if (tid < st) { s1[tid] += s1[tid + st]; s2[tid] += s2[tid + st]; }
    __syncthreads();
  }
  if (tid == 0) {
    float m = s1[0] * (1.f / 4096.f);
    float var = s2[0] * (1.f / 4096.f) - m * m;
    mean[bc] = m;
    rstd[bc] = rsqrtf(var + EPSV);
  }
}

// ---------------- kernel 2: conv_w[o][c][3][3] -> wT2 MFMA-fragment layout bf16
// flat = (((t*32 + o/16)*16 + c/32)*64 + (g*16 + o%16))*8 + e, g=(c%32)/8, e=c%8
__global__ __launch_bounds__(256) void k_wprep(const float* __restrict__ cw,
                                               unsigned short* __restrict__ wT2) {
  int idx = blockIdx.x * 256 + threadIdx.x;  // 9*512*512
  int e = idx & 7;
  int l15 = (idx >> 3) & 15;
  int g = (idx >> 7) & 3;
  int cq = (idx >> 9) & 15;
  int og = (idx >> 13) & 31;
  int t = idx >> 18;
  int o = og * 16 + l15;
  int c = cq * 32 + g * 8 + e;
  wT2[idx] = f2bf(cw[((size_t)(o * 512 + c)) * 9 + t]);
}

// ---------------- kernel 3: fused IN + dw3x3 + pointwise + bias -> mid bf16 [b][h][w][c]
__global__ __launch_bounds__(256) void k_mid(const float* __restrict__ x,
                                             const float* __restrict__ wsp,
                                             const float* __restrict__ wpw,
                                             const float* __restrict__ bias,
                                             const float* __restrict__ mean,
                                             const float* __restrict__ rstd,
                                             unsigned short* __restrict__ mid) {
  int bid = blockIdx.x;                      // 8 * 16 * 4 = 512
  int cg = bid & 3;
  int hq = (bid >> 2) & 15;
  int b = bid >> 6;
  int h0 = hq * 4;
  int tid = threadIdx.x;
  int cl = tid & 31, wq = tid >> 5;
  __shared__ float xs[32 * 391];

  int rowm[6];
#pragma unroll
  for (int r = 0; r < 6; ++r) rowm[r] = refl(h0 - 1 + r, 64);

  for (int cc = 0; cc < 4; ++cc) {
    int cbase = cg * 128 + cc * 32;
    __syncthreads();
#pragma unroll
    for (int k = 0; k < 12; ++k) {
      int idx = tid + k * 256;
      int c = idx / 96, rem = idx % 96;
      int r = rem >> 4, w4 = rem & 15;
      float4 v = *(const float4*)(x + ((size_t)(b * 512 + cbase + c)) * 4096 +
                                  rowm[r] * 64 + w4 * 4);
      float* dst = &xs[c * 391 + r * 65 + w4 * 4];
      dst[0] = v.x; dst[1] = v.y; dst[2] = v.z; dst[3] = v.w;
    }
    __syncthreads();

    int gc = b * 512 + cbase + cl;
    float m = mean[gc], rs = rstd[gc];
    float wp = wpw[gc], bv = bias[gc];
    float wk[9], wsum = 0.f;
#pragma unroll
    for (int t = 0; t < 9; ++t) { wk[t] = wsp[(size_t)gc * 9 + t]; wsum += wk[t]; }

    const float* xr = &xs[cl * 391];
#pragma unroll
    for (int r = 0; r < 4; ++r) {
#pragma unroll
      for (int wi = 0; wi < 8; ++wi) {
        int w = wq * 8 + wi;
        int wm = refl(w - 1, 64), wp1 = refl(w + 1, 64);
        float acc = 0.f;
#pragma unroll
        for (int dy = 0; dy < 3; ++dy) {
          const float* row = xr + (r + dy) * 65;
          acc += wk[dy * 3 + 0] * row[wm] + wk[dy * 3 + 1] * row[w] +
                 wk[dy * 3 + 2] * row[wp1];
        }
        float y = (acc - m * wsum) * rs;
        mid[(((size_t)(b * 64 + h0 + r)) * 64 + w) * 512 + cbase + cl] =
            f2bf(y * wp + bv);
      }
    }
  }
}

// ---------------- kernel 4: final 3x3 conv, implicit GEMM ----------------
// grid 512; 8 waves; block = 256 o x (2 rows x 64 w). c-chunks of 32.
// A chunk (256o x 32c, one t) and B chunk (4 rows x 64w x 32c) both async-staged.
__global__ __launch_bounds__(512, 4) void k_conv(const unsigned short* __restrict__ wT2,
                                                 const unsigned short* __restrict__ mid,
                                                 const float* __restrict__ cb,
                                                 float* __restrict__ out) {
  int nbid = (blockIdx.x & 7) * 64 + (blockIdx.x >> 3);  // XCD-chunked bijection
  int mt = nbid >> 8;                        // 0..1 (256 o each)
  int b = (nbid >> 5) & 7;
  int h0 = (nbid & 31) * 2;
  int tid = threadIdx.x;
  int wid = tid >> 6, l = tid & 63;
  int wo = wid >> 1, wn = wid & 1;
  int l15 = l & 15, g = l >> 4;

  __shared__ union {
    struct {
      unsigned short bbuf[2][4 * 64 * 32];   // 2 x 16 KB (mid tile)
      unsigned short abuf[2][16 * 64 * 8];   // 2 x 16 KB (weight chunk)
    } s;
    float epi[128 * 132];                    // epilogue transpose (padded)
  } sm;

  int hrow_[4];
  hrow_[0] = refl(h0 - 1, 64); hrow_[1] = h0; hrow_[2] = h0 + 1;
  hrow_[3] = refl(h0 + 2, 64);

  int wrv[4][3];
#pragma unroll
  for (int nf = 0; nf < 4; ++nf)
#pragma unroll
    for (int dx = 0; dx < 3; ++dx)
      wrv[nf][dx] = refl(nf * 16 + l15 + dx - 1, 64);

  f32x4 acc[4][4];
  f32x4 zero = {0.f, 0.f, 0.f, 0.f};
#pragma unroll
  for (int i = 0; i < 4; ++i)
#pragma unroll
    for (int j = 0; j < 4; ++j) acc[i][j] = zero;

  // B: one 32-c chunk (4 rows x 64 w x 32 c = 16 KB), linear dest, swizzled src
  auto stageB = [&](int pi, int cc) {
    int cb32 = cc * 32;
    char* dstbase = (char*)&sm.s.bbuf[pi][0];
#pragma unroll
    for (int i = 0; i < 2; ++i) {
      int ld = tid + i * 512;                // 0..1023
      int row = ld >> 8, rem = ld & 255, w = rem >> 2, s = rem & 3;
      int gcg = s ^ ((w >> 1) & 3);
      const unsigned short* src = mid +
          (((size_t)(b * 64 + hrow_[row])) * 64 + w) * 512 + cb32 + gcg * 8;
      __builtin_amdgcn_global_load_lds(
          (const __attribute__((address_space(1))) void*)src,
          (__attribute__((address_space(3))) void*)(dstbase + ld * 16),
          16, 0, 0);
    }
  };

  // A: weights for (cc, t): 16 o-groups x 16 lanes x 16B = 16 KB
  auto stageA = [&](int ai, int cc, int t) {
    char* dstbase = (char*)&sm.s.abuf[ai][0];
#pragma unroll
    for (int r = 0; r < 2; ++r) {
      int id = r * 512 + tid;                // 0..1023
      int piece = id >> 6, le = id & 63;
      const unsigned short* src = wT2 +
          (((size_t)(t * 32 + mt * 16 + piece)) * 16 + cc) * 512 + le * 8;
      __builtin_amdgcn_global_load_lds(
          (const __attribute__((address_space(1))) void*)src,
          (__attribute__((address_space(3))) void*)(dstbase + id * 16),
          16, 0, 0);
    }
  };

  stageB(0, 0);
  stageA(0, 0, 0);
  int ai = 0;
  for (int cc = 0; cc < 16; ++cc) {
    int pb = cc & 1;
#pragma unroll
    for (int t = 0; t < 9; ++t) {
      __syncthreads();                       // A(cc,t) [+ B(cc) at t==0] landed
      if (t < 8) stageA(ai ^ 1, cc, t + 1);
      else if (cc < 15) stageA(ai ^ 1, cc + 1, 0);
      if (t == 0 && cc < 15) stageB(pb ^ 1, cc + 1);

      const int dy = t / 3, dx = t % 3;      // compile-time (t unrolled)
      const int rowL = wn + dy;
      const char* mb = (const char*)&sm.s.bbuf[pb][0];
      const char* ab = (const char*)&sm.s.abuf[ai][0];

      short8 bfr[4];
#pragma unroll
      for (int nf = 0; nf < 4; ++nf) {
        int wr = wrv[nf][dx];
        int s = g ^ ((wr >> 1) & 3);
        bfr[nf] = *(const short8*)(mb + rowL * 4096 + wr * 64 + s * 16);
      }
      short8 afr[4];
#pragma unroll
      for (int of = 0; of < 4; ++of)
        afr[of] = *(const short8*)(ab + ((wo * 4 + of) * 64 + l) * 16);

      __builtin_amdgcn_s_setprio(1);
#pragma unroll
      for (int of = 0; of < 4; ++of)
#pragma unroll
        for (int nf = 0; nf < 4; ++nf)
          acc[of][nf] = __builtin_amdgcn_mfma_f32_16x16x32_bf16(
              afr[of], bfr[nf], acc[of][nf], 0, 0, 0);
      __builtin_amdgcn_s_setprio(0);
      ai ^= 1;
    }
  }

  // ---- epilogue: LDS transpose -> coalesced float4 row stores ----
#pragma unroll
  for (int p = 0; p < 2; ++p) {
    __syncthreads();
    if ((wo >> 1) == p) {
      int ol_base = (wo & 1) * 64;
#pragma unroll
      for (int of = 0; of < 4; ++of)
#pragma unroll
        for (int nf = 0; nf < 4; ++nf) {
          int pix = wn * 64 + nf * 16 + l15;
#pragma unroll
          for (int r = 0; r < 4; ++r) {
            int ol = ol_base + of * 16 + g * 4 + r;
            sm.epi[ol * 132 + pix] = acc[of][nf][r];
          }
        }
    }
    __syncthreads();
#pragma unroll
    for (int k = 0; k < 8; ++k) {
      int idx = tid + k * 512;               // 0..4095 float4 units
      int ol = idx >> 5, rem = idx & 31;
      float4 v = *(const float4*)&sm.epi[ol * 132 + rem * 4];
      int o = mt * 256 + p * 128 + ol;
      float cbv = cb[o];
      v.x += cbv; v.y += cbv; v.z += cbv; v.w += cbv;
      int hh = h0 + (rem >> 4);
      int w4 = (rem & 15) * 4;
      *(float4*)(out + (((size_t)(b * 512 + o)) * 64 + hh) * 64 + w4) = v;
    }
  }
}

extern "C" void kernel_launch(void* const* d_in, const int* in_sizes, int n_in,
                              void* d_out, int out_size, void* d_ws, size_t ws_size,
                              hipStream_t stream) {
  const float* x    = (const float*)d_in[0];
  const float* wsp  = (const float*)d_in[1];
  const float* wpw  = (const float*)d_in[2];
  const float* bias = (const float*)d_in[3];
  const float* cw   = (const float*)d_in[4];
  const float* cb   = (const float*)d_in[5];
  float* out = (float*)d_out;

  char* ws = (char*)d_ws;
  float* mean = (float*)ws;                              // 4096 f32
  float* rstd = (float*)(ws + 16384);                    // 4096 f32
  unsigned short* wT2 = (unsigned short*)(ws + 32768);   // 4.5 MB
  unsigned short* mid = (unsigned short*)(ws + 32768 + 9 * 512 * 512 * 2); // 32 MB

  k_stats<<<4096, 256, 0, stream>>>(x, mean, rstd);
  k_wprep<<<9216, 256, 0, stream>>>(cw, wT2);
  k_mid<<<512, 256, 0, stream>>>(x, wsp, wpw, bias, mean, rstd, mid);
  k_conv<<<512, 512, 0, stream>>>(wT2, mid, cb, out);
}

// Round 5
// 277.155 us; speedup vs baseline: 1.5425x; 1.0346x over previous
//
#include <hip/hip_runtime.h>
#include <hip/hip_bf16.h>

// Pipeline: k_stats (IN mean/rstd) -> k_wprep (conv_w -> bf16 wT2 fragment layout)
//           k_mid (fused IN+dw3x3+pw+bias -> mid bf16 [b][h][w][c])
//           k_conv (implicit-GEMM 3x3 conv, MFMA 16x16x32; counted-vmcnt pipeline:
//                   A staged 2 phases deep (3 bufs), B 1 chunk deep (2 bufs),
//                   raw s_barrier, vmcnt never drained to 0 in the main loop)

#define EPSV 1e-5f

typedef __attribute__((ext_vector_type(8))) short short8;
typedef __attribute__((ext_vector_type(4))) float f32x4;

#define WAITVM(n) asm volatile("s_waitcnt vmcnt(" #n ")" ::: "memory")

__device__ __forceinline__ unsigned short f2bf(float f) {
  union { float f; unsigned int u; } v; v.f = f;
  unsigned int r = v.u + 0x7FFFu + ((v.u >> 16) & 1u);   // RNE
  return (unsigned short)(r >> 16);
}

__device__ __forceinline__ int refl(int i, int n) {
  if (i < 0) i = -i;
  if (i >= n) i = 2 * n - 2 - i;
  return i;
}

// ---------------- kernel 1: instance-norm stats ----------------
__global__ __launch_bounds__(256) void k_stats(const float* __restrict__ x,
                                               float* __restrict__ mean,
                                               float* __restrict__ rstd) {
  int bc = blockIdx.x;
  const float4* xp = (const float4*)(x + (size_t)bc * 4096);
  int tid = threadIdx.x;
  float s = 0.f, q = 0.f;
#pragma unroll
  for (int k = 0; k < 4; ++k) {
    float4 v = xp[tid + k * 256];
    s += v.x + v.y + v.z + v.w;
    q += v.x * v.x + v.y * v.y + v.z * v.z + v.w * v.w;
  }
  __shared__ float s1[256], s2[256];
  s1[tid] = s; s2[tid] = q;
  __syncthreads();
  for (int st = 128; st > 0; st >>= 1) {
    if (tid < st) { s1[tid] += s1[tid + st]; s2[tid] += s2[tid + st]; }
    __syncthreads();
  }
  if (tid == 0) {
    float m = s1[0] * (1.f / 4096.f);
    float var = s2[0] * (1.f / 4096.f) - m * m;
    mean[bc] = m;
    rstd[bc] = rsqrtf(var + EPSV);
  }
}

// ---------------- kernel 2: conv_w[o][c][3][3] -> wT2 MFMA-fragment layout bf16
// flat = (((t*32 + o/16)*16 + c/32)*64 + (g*16 + o%16))*8 + e, g=(c%32)/8, e=c%8
__global__ __launch_bounds__(256) void k_wprep(const float* __restrict__ cw,
                                               unsigned short* __restrict__ wT2) {
  int idx = blockIdx.x * 256 + threadIdx.x;  // 9*512*512
  int e = idx & 7;
  int l15 = (idx >> 3) & 15;
  int g = (idx >> 7) & 3;
  int cq = (idx >> 9) & 15;
  int og = (idx >> 13) & 31;
  int t = idx >> 18;
  int o = og * 16 + l15;
  int c = cq * 32 + g * 8 + e;
  wT2[idx] = f2bf(cw[((size_t)(o * 512 + c)) * 9 + t]);
}

// ---------------- kernel 3: fused IN + dw3x3 + pointwise + bias -> mid bf16 [b][h][w][c]
__global__ __launch_bounds__(256) void k_mid(const float* __restrict__ x,
                                             const float* __restrict__ wsp,
                                             const float* __restrict__ wpw,
                                             const float* __restrict__ bias,
                                             const float* __restrict__ mean,
                                             const float* __restrict__ rstd,
                                             unsigned short* __restrict__ mid) {
  int bid = blockIdx.x;                      // 8 * 16 * 4 = 512
  int cg = bid & 3;
  int hq = (bid >> 2) & 15;
  int b = bid >> 6;
  int h0 = hq * 4;
  int tid = threadIdx.x;
  int cl = tid & 31, wq = tid >> 5;
  __shared__ float xs[32 * 391];

  int rowm[6];
#pragma unroll
  for (int r = 0; r < 6; ++r) rowm[r] = refl(h0 - 1 + r, 64);

  for (int cc = 0; cc < 4; ++cc) {
    int cbase = cg * 128 + cc * 32;
    __syncthreads();
#pragma unroll
    for (int k = 0; k < 12; ++k) {
      int idx = tid + k * 256;
      int c = idx / 96, rem = idx % 96;
      int r = rem >> 4, w4 = rem & 15;
      float4 v = *(const float4*)(x + ((size_t)(b * 512 + cbase + c)) * 4096 +
                                  rowm[r] * 64 + w4 * 4);
      float* dst = &xs[c * 391 + r * 65 + w4 * 4];
      dst[0] = v.x; dst[1] = v.y; dst[2] = v.z; dst[3] = v.w;
    }
    __syncthreads();

    int gc = b * 512 + cbase + cl;
    float m = mean[gc], rs = rstd[gc];
    float wp = wpw[gc], bv = bias[gc];
    float wk[9], wsum = 0.f;
#pragma unroll
    for (int t = 0; t < 9; ++t) { wk[t] = wsp[(size_t)gc * 9 + t]; wsum += wk[t]; }

    const float* xr = &xs[cl * 391];
#pragma unroll
    for (int r = 0; r < 4; ++r) {
#pragma unroll
      for (int wi = 0; wi < 8; ++wi) {
        int w = wq * 8 + wi;
        int wm = refl(w - 1, 64), wp1 = refl(w + 1, 64);
        float acc = 0.f;
#pragma unroll
        for (int dy = 0; dy < 3; ++dy) {
          const float* row = xr + (r + dy) * 65;
          acc += wk[dy * 3 + 0] * row[wm] + wk[dy * 3 + 1] * row[w] +
                 wk[dy * 3 + 2] * row[wp1];
        }
        float y = (acc - m * wsum) * rs;
        mid[(((size_t)(b * 64 + h0 + r)) * 64 + w) * 512 + cbase + cl] =
            f2bf(y * wp + bv);
      }
    }
  }
}

// ---------------- kernel 4: final 3x3 conv, implicit GEMM, counted-vmcnt pipeline ----
// grid 512; 8 waves; block = 256 o x (2 rows x 64 w). 144 phases = 16 cc x 9 t.
// Phase k uses A buf (t%3) [9 = 0 mod 3 -> compile-time], B buf (cc&1).
__global__ __launch_bounds__(512, 4) void k_conv(const unsigned short* __restrict__ wT2,
                                                 const unsigned short* __restrict__ mid,
                                                 const float* __restrict__ cb,
                                                 float* __restrict__ out) {
  int nbid = (blockIdx.x & 7) * 64 + (blockIdx.x >> 3);  // XCD-chunked bijection
  int mt = nbid >> 8;                        // 0..1 (256 o each)
  int b = (nbid >> 5) & 7;
  int h0 = (nbid & 31) * 2;
  int tid = threadIdx.x;
  int wid = tid >> 6, l = tid & 63;
  int wo = wid >> 1, wn = wid & 1;
  int l15 = l & 15, g = l >> 4;

  __shared__ union {
    struct {
      unsigned short bbuf[2][4 * 64 * 32];   // 2 x 16 KB (mid tile)
      unsigned short abuf[3][16 * 64 * 8];   // 3 x 16 KB (weight chunk)
    } s;
    float epi[64 * 132];                     // epilogue transpose (aliases bbuf+)
  } sm;

  int hrow_[4];
  hrow_[0] = refl(h0 - 1, 64); hrow_[1] = h0; hrow_[2] = h0 + 1;
  hrow_[3] = refl(h0 + 2, 64);

  int wrv[4][3];
#pragma unroll
  for (int nf = 0; nf < 4; ++nf)
#pragma unroll
    for (int dx = 0; dx < 3; ++dx)
      wrv[nf][dx] = refl(nf * 16 + l15 + dx - 1, 64);

  f32x4 acc[4][4];
  f32x4 zero = {0.f, 0.f, 0.f, 0.f};
#pragma unroll
  for (int i = 0; i < 4; ++i)
#pragma unroll
    for (int j = 0; j < 4; ++j) acc[i][j] = zero;

  // B: one 32-c chunk (4 rows x 64 w x 32 c = 16 KB), linear dest, swizzled src
  auto stageB = [&](int pi, int cc) {
    int cb32 = cc * 32;
    char* dstbase = (char*)&sm.s.bbuf[pi][0];
#pragma unroll
    for (int i = 0; i < 2; ++i) {
      int ld = tid + i * 512;                // 0..1023
      int row = ld >> 8, rem = ld & 255, w = rem >> 2, s = rem & 3;
      int gcg = s ^ ((w >> 1) & 3);
      const unsigned short* src = mid +
          (((size_t)(b * 64 + hrow_[row])) * 64 + w) * 512 + cb32 + gcg * 8;
      __builtin_amdgcn_global_load_lds(
          (const __attribute__((address_space(1))) void*)src,
          (__attribute__((address_space(3))) void*)(dstbase + ld * 16),
          16, 0, 0);
    }
  };

  // A: weights for (cc, t): 16 o-groups x 64 lanes x 16B = 16 KB
  auto stageA = [&](int bufi, int cc2, int t2) {
    char* dstbase = (char*)&sm.s.abuf[bufi][0];
#pragma unroll
    for (int r = 0; r < 2; ++r) {
      int id = r * 512 + tid;                // 0..1023
      int piece = id >> 6, le = id & 63;
      const unsigned short* src = wT2 +
          (((size_t)(t2 * 32 + mt * 16 + piece)) * 16 + cc2) * 512 + le * 8;
      __builtin_amdgcn_global_load_lds(
          (const __attribute__((address_space(1))) void*)src,
          (__attribute__((address_space(3))) void*)(dstbase + id * 16),
          16, 0, 0);
    }
  };

  // prologue: FIFO = B(0)[2], A(k=0)[2], A(k=1)[2]
  stageB(0, 0);
  stageA(0, 0, 0);
  stageA(1, 0, 1);

  for (int cc = 0; cc < 16; ++cc) {
    int pb = cc & 1;
#pragma unroll
    for (int t = 0; t < 9; ++t) {
      // wait: A(k) landed (FIFO: 2 newer loads, +2 if B issued at phase k-1,
      // i.e. t==1 && cc<15; final phase drains everything)
      if (t == 1)      { if (cc < 15) { WAITVM(4); } else { WAITVM(2); } }
      else if (t == 8) { if (cc == 15) { WAITVM(0); } else { WAITVM(2); } }
      else             { WAITVM(2); }
      __builtin_amdgcn_s_barrier();
      asm volatile("" ::: "memory");

      // issue next stages (buffers freed by phase k-1, protected by the barrier)
      if (t == 0 && cc < 15) stageB(pb ^ 1, cc + 1);
      if (t < 7)            stageA((t + 2) % 3, cc, t + 2);
      else if (cc < 15)     stageA((t + 2) % 3, cc + 1, t - 7);

      const int dy = t / 3, dx = t % 3;      // compile-time (t unrolled)
      const int rowL = wn + dy;
      const char* mb = (const char*)&sm.s.bbuf[pb][0];
      const char* ab = (const char*)&sm.s.abuf[t % 3][0];

      short8 bfr[4];
#pragma unroll
      for (int nf = 0; nf < 4; ++nf) {
        int wr = wrv[nf][dx];
        int s = g ^ ((wr >> 1) & 3);
        bfr[nf] = *(const short8*)(mb + rowL * 4096 + wr * 64 + s * 16);
      }
      short8 afr[4];
#pragma unroll
      for (int of = 0; of < 4; ++of)
        afr[of] = *(const short8*)(ab + ((wo * 4 + of) * 64 + l) * 16);

      __builtin_amdgcn_s_setprio(1);
#pragma unroll
      for (int of = 0; of < 4; ++of)
#pragma unroll
        for (int nf = 0; nf < 4; ++nf)
          acc[of][nf] = __builtin_amdgcn_mfma_f32_16x16x32_bf16(
              afr[of], bfr[nf], acc[of][nf], 0, 0, 0);
      __builtin_amdgcn_s_setprio(0);
    }
  }

  // ---- epilogue: LDS transpose -> coalesced float4 row stores ----
#pragma unroll
  for (int p = 0; p < 4; ++p) {
    __syncthreads();
    if (wo == p) {
#pragma unroll
      for (int of = 0; of < 4; ++of)
#pragma unroll
        for (int nf = 0; nf < 4; ++nf) {
          int pix = wn * 64 + nf * 16 + l15;
#pragma unroll
          for (int r = 0; r < 4; ++r) {
            int ol = of * 16 + g * 4 + r;
            sm.epi[ol * 132 + pix] = acc[of][nf][r];
          }
        }
    }
    __syncthreads();
#pragma unroll
    for (int it = 0; it < 4; ++it) {
      int idx = tid + it * 512;              // 0..2047 float4 units
      int ol = idx >> 5, rem = idx & 31;
      float4 v = *(const float4*)&sm.epi[ol * 132 + rem * 4];
      int o = mt * 256 + p * 64 + ol;
      float cbv = cb[o];
      v.x += cbv; v.y += cbv; v.z += cbv; v.w += cbv;
      int hh = h0 + (rem >> 4);
      int w4 = (rem & 15) * 4;
      *(float4*)(out + (((size_t)(b * 512 + o)) * 64 + hh) * 64 + w4) = v;
    }
  }
}

extern "C" void kernel_launch(void* const* d_in, const int* in_sizes, int n_in,
                              void* d_out, int out_size, void* d_ws, size_t ws_size,
                              hipStream_t stream) {
  const float* x    = (const float*)d_in[0];
  const float* wsp  = (const float*)d_in[1];
  const float* wpw  = (const float*)d_in[2];
  const float* bias = (const float*)d_in[3];
  const float* cw   = (const float*)d_in[4];
  const float* cb   = (const float*)d_in[5];
  float* out = (float*)d_out;

  char* ws = (char*)d_ws;
  float* mean = (float*)ws;                              // 4096 f32
  float* rstd = (float*)(ws + 16384);                    // 4096 f32
  unsigned short* wT2 = (unsigned short*)(ws + 32768);   // 4.5 MB
  unsigned short* mid = (unsigned short*)(ws + 32768 + 9 * 512 * 512 * 2); // 32 MB

  k_stats<<<4096, 256, 0, stream>>>(x, mean, rstd);
  k_wprep<<<9216, 256, 0, stream>>>(cw, wT2);
  k_mid<<<512, 256, 0, stream>>>(x, wsp, wpw, bias, mean, rstd, mid);
  k_conv<<<512, 512, 0, stream>>>(wT2, mid, cb, out);
}